// Round 9
// baseline (213.634 us; speedup 1.0000x reference)
//
#include <hip/hip_runtime.h>
#include <hip/hip_bf16.h>

typedef unsigned short u16;
typedef unsigned int u32;
typedef short bf16x8 __attribute__((ext_vector_type(8)));
typedef float f32x4 __attribute__((ext_vector_type(4)));
typedef u16 u16x8 __attribute__((ext_vector_type(8)));

#define HID 1024
#define BATCH 4096
#define KTOT 2048       // concat K: [x | h_prev]
#define NT 64           // K tiles of 32
// LDS element-index region bases: [A buf0 | A buf1 | B buf0 | B buf1]
#define A0B 0
#define A1B 8192
#define B0B 16384
#define B1B 20480

__device__ __forceinline__ u16 f2bf(float f) {
  u32 v = __builtin_bit_cast(u32, f);
  u32 r = (v + 0x7fffu + ((v >> 16) & 1u)) >> 16;  // round-nearest-even
  return (u16)r;
}
__device__ __forceinline__ float sigmoid_fast(float x) {
  return 1.0f / (1.0f + __expf(-x));
}
__device__ __forceinline__ float tanh_fast(float x) {
  return 2.0f * sigmoid_fast(2.0f * x) - 1.0f;
}
__device__ __forceinline__ void gl_lds16(const void* g, void* l) {
  __builtin_amdgcn_global_load_lds(
      (const __attribute__((address_space(1))) u32*)g,
      (__attribute__((address_space(3))) u32*)l, 16, 0, 0);
}

// ---------------------------------------------------------------------------
// prep_all: fused prep. Blocks [0,4096) build xh (bf16 [B][2048]); blocks
// [4096,6144) build Bt[n'][k] (bf16, gate-interleaved n') via LDS transpose.
// ---------------------------------------------------------------------------
__global__ __launch_bounds__(256) void prep_all(
    const float* __restrict__ x, const float* __restrict__ hp,
    const float* __restrict__ igx, const float* __restrict__ fgx,
    const float* __restrict__ ogx, const float* __restrict__ cgx,
    const float* __restrict__ igu, const float* __restrict__ fgu,
    const float* __restrict__ ogu, const float* __restrict__ cgu,
    u16* __restrict__ xh, u16* __restrict__ bt) {
  __shared__ u16 lds[64 * 66];
  if (blockIdx.x < 4096) {
    int c = blockIdx.x * 256 + threadIdx.x;  // chunk id, 8 elems each
    int row = c >> 8;
    int col0 = (c & 255) << 3;
    const float* src = (col0 < 1024)
                           ? (x + (size_t)row * 1024 + col0)
                           : (hp + (size_t)row * 1024 + (col0 - 1024));
    f32x4 a = *(const f32x4*)(src);
    f32x4 b = *(const f32x4*)(src + 4);
    u16x8 v;
#pragma unroll
    for (int j = 0; j < 4; ++j) { v[j] = f2bf(a[j]); v[j + 4] = f2bf(b[j]); }
    *(u16x8*)(xh + (size_t)row * KTOT + col0) = v;
    return;
  }
  // ---- weight transpose: n' = (h/16)*64 + g*16 + (h%16), k = which*1024+ksrc
  const float* srcs[8] = {igx, fgx, ogx, cgx, igu, fgu, ogu, cgu};
  int bid = blockIdx.x - 4096;
  int m = bid >> 8;            // matrix 0..7
  int tile = bid & 255;        // 64x64 tile
  int th = tile & 15, tk = tile >> 4;
  int h0 = th << 6, k0 = tk << 6;
  int g = m & 3, which = m >> 2;
  const float* W = srcs[m] + (size_t)k0 * HID + h0;

  int t = threadIdx.x;
  int r1 = t >> 4;
  int c1 = (t & 15) << 2;
#pragma unroll
  for (int p = 0; p < 4; ++p) {
    int row = (p << 4) + r1;
    f32x4 v = *(const f32x4*)(W + (size_t)row * HID + c1);
    u32 p0 = (u32)f2bf(v[0]) | ((u32)f2bf(v[1]) << 16);
    u32 p1 = (u32)f2bf(v[2]) | ((u32)f2bf(v[3]) << 16);
    u32* d = (u32*)&lds[row * 66 + c1];
    d[0] = p0;
    d[1] = p1;
  }
  __syncthreads();
  int nl = t >> 2;
  int kc = t & 3;
  int row_np = ((h0 >> 4) << 6) + ((nl >> 4) << 6) + (g << 4) + (nl & 15);
  size_t dst = (size_t)row_np * KTOT + (size_t)which * 1024 + k0;
  u16x8 a2, b2;
#pragma unroll
  for (int j = 0; j < 8; ++j) {
    a2[j] = lds[(kc * 8 + j) * 66 + nl];
    b2[j] = lds[(kc * 8 + 32 + j) * 66 + nl];
  }
  *(u16x8*)(&bt[dst + kc * 8]) = a2;
  *(u16x8*)(&bt[dst + kc * 8 + 32]) = b2;
}

// ---------------------------------------------------------------------------
// lstm_gemm (R9): 256M x 128N tile, 256 threads (4 waves, 2Mx2N: each wave
// 128x64, acc 8x4 f32x4 = 128 regs — per-wave structure unchanged), BK=32,
// 48 KiB LDS dbuf -> grid 16x32 = 512 blocks = TWO co-resident blocks/CU.
// Two independent barrier domains per CU phase-shift naturally, so one
// block's LDS read/DMA burst overlaps the other's MFMA burst — the
// cross-overlap that 8 in-block schedule variants (R1-R8) could not create
// (1 block/CU lockstep alternated pipes; per-tile time = LDS + MFMA sum).
// Per-FLOP LDS amplification unchanged (22.9 KB/MFLOP). 16x16x32 MFMA
// (R8's 32x32 shape regressed: bank conflicts). XOR k-chunk swizzle in
// 4-chunk space (slot ^= row&3) via pre-swizzled global source; fragment
// reads land 2-way/bank in 8-lane groups = free (m136). One barrier per
// K-tile, stage-at-top, T1 XCD swizzle (bijective for 512), fused epilogue.
// ---------------------------------------------------------------------------
__global__ __launch_bounds__(256, 2) void lstm_gemm(
    const u16* __restrict__ xh, const u16* __restrict__ bt,
    const float* __restrict__ cprev,
    const float* __restrict__ ib, const float* __restrict__ fb,
    const float* __restrict__ ob, const float* __restrict__ cb,
    float* __restrict__ hout, float* __restrict__ cout) {
  __shared__ __align__(16) u16 lds[24576];   // 48 KiB

  int sx = threadIdx.x;
  // T1: bid%8 -> XCD; XCD k owns brows [4*(k&3),+4), bcols [16*(k>>2),+16)
  int bid = blockIdx.x;
  int xcd = bid & 7, lid = bid >> 3;               // lid 0..63
  int brow = ((xcd & 3) << 2) | (lid & 3);         // 0..15
  int bcol = ((xcd >> 2) << 4) | (lid >> 2);       // 0..31

  int w = sx >> 6, l = sx & 63;
  int wr = (w >> 1) << 7;              // 0 | 128 (WARPS_M = 2)
  int wc = (w & 1) << 6;               // 0 | 64  (WARPS_N = 2)
  int lrow = l & 15, q = l >> 4;
  int grow = brow << 8;

  // staging source pointers (per-lane global addr carries the k-chunk swizzle)
  int prow = sx >> 2;                                    // 0..63
  int koff = ((sx & 3) ^ (prow & 3)) << 3;               // swizzled k elems
  const u16* aS = xh + (size_t)(grow + prow) * KTOT + koff;
  const u16* bS = bt + (size_t)(bcol * 128 + prow) * KTOT + koff;
  int sx8 = sx * 8;

  // fragment read offsets: physical chunk = logical ^ (row&3); row&3==lrow&3
  int arow_l = (wr + lrow) << 5;            // *32 elems per row
  int brow_l = (wc + lrow) << 5;
  int pc = (q ^ (lrow & 3)) << 3;           // lane's k-chunk (q = l>>4)

  f32x4 acc[8][4] = {};
  bf16x8 af[8], bfr[4];

  // stage one K-tile (A 256 rows + B 128 rows) into bases AD_, BD_
#define STG(KK_, AD_, BD_)                                                    \
  gl_lds16(aS + (KK_), &lds[(AD_) + sx8]);                                    \
  gl_lds16(aS + (size_t)64 * KTOT + (KK_), &lds[(AD_) + 2048 + sx8]);         \
  gl_lds16(aS + (size_t)128 * KTOT + (KK_), &lds[(AD_) + 4096 + sx8]);        \
  gl_lds16(aS + (size_t)192 * KTOT + (KK_), &lds[(AD_) + 6144 + sx8]);        \
  gl_lds16(bS + (KK_), &lds[(BD_) + sx8]);                                    \
  gl_lds16(bS + (size_t)64 * KTOT + (KK_), &lds[(BD_) + 2048 + sx8]);

  // interior: 12 b128 reads + 32 MFMA, compiler-scheduled (partial lgkmcnt)
#define INTERIOR(AC_, BC_)                                                    \
  bfr[0] = *(const bf16x8*)&lds[(BC_) + brow_l + 0 * 512 + pc];               \
  bfr[1] = *(const bf16x8*)&lds[(BC_) + brow_l + 1 * 512 + pc];               \
  bfr[2] = *(const bf16x8*)&lds[(BC_) + brow_l + 2 * 512 + pc];               \
  bfr[3] = *(const bf16x8*)&lds[(BC_) + brow_l + 3 * 512 + pc];               \
  _Pragma("unroll") for (int i = 0; i < 8; ++i)                               \
      af[i] = *(const bf16x8*)&lds[(AC_) + arow_l + i * 512 + pc];            \
  _Pragma("unroll") for (int i = 0; i < 8; ++i) {                             \
    _Pragma("unroll") for (int j = 0; j < 4; ++j) {                           \
      acc[i][j] = __builtin_amdgcn_mfma_f32_16x16x32_bf16(                    \
          af[i], bfr[j], acc[i][j], 0, 0, 0);                                 \
    }                                                                         \
  }

#define TILE(AC_, BC_, KN_, AD_, BD_)                                         \
  {                                                                           \
    STG((KN_), (AD_), (BD_))                                                  \
    __builtin_amdgcn_sched_barrier(0);                                        \
    INTERIOR(AC_, BC_)                                                        \
  }

  // prologue: tile 0
  STG(0, A0B, B0B)
  __syncthreads();

  // tiles 0..61 in pairs; stage tile t+1 into the other buffer
  for (int tp = 0; tp < 31; ++tp) {
    int k1 = (2 * tp + 1) << 5;
    int k2 = (2 * tp + 2) << 5;
    TILE(A0B, B0B, k1, A1B, B1B)
    __syncthreads();
    TILE(A1B, B1B, k2, A0B, B0B)
    __syncthreads();
  }
  // tile 62: stage tile 63; tile 63: no stage
  TILE(A0B, B0B, 63 << 5, A1B, B1B)
  __syncthreads();
  INTERIOR(A1B, B1B)

#undef TILE
#undef INTERIOR
#undef STG

  // Epilogue: n-frag j = gate (i,f,o,c) for hidden cols of sub-block sb.
  int sb = (bcol << 1) + (w & 1);
  int hcol = (sb << 4) + lrow;
  float bi = ib[hcol];
  float bff = fb[hcol];
  float bo = ob[hcol];
  float bc = cb[hcol];

#pragma unroll
  for (int i = 0; i < 8; ++i) {
    int row0 = grow + wr + i * 16 + q * 4;
#pragma unroll
    for (int r = 0; r < 4; ++r) {
      size_t idx = (size_t)(row0 + r) * HID + hcol;
      float gi = sigmoid_fast(acc[i][0][r] + bi);
      float gf = sigmoid_fast(acc[i][1][r] + bff);
      float go = sigmoid_fast(acc[i][2][r] + bo);
      float gc = tanh_fast(acc[i][3][r] + bc);
      float cp = cprev[idx];
      float cv = gf * cp + gi * gc;
      hout[idx] = go * tanh_fast(cv);
      cout[idx] = cv;
    }
  }
}

extern "C" void kernel_launch(void* const* d_in, const int* in_sizes, int n_in,
                              void* d_out, int out_size, void* d_ws, size_t ws_size,
                              hipStream_t stream) {
  const float* x   = (const float*)d_in[0];
  const float* hp  = (const float*)d_in[1];
  const float* cp  = (const float*)d_in[2];
  const float* igx = (const float*)d_in[3];
  const float* igu = (const float*)d_in[4];
  const float* ib  = (const float*)d_in[5];
  const float* fgx = (const float*)d_in[6];
  const float* fgu = (const float*)d_in[7];
  const float* fb  = (const float*)d_in[8];
  const float* ogx = (const float*)d_in[9];
  const float* ogu = (const float*)d_in[10];
  const float* ob  = (const float*)d_in[11];
  const float* cgx = (const float*)d_in[12];
  const float* cgu = (const float*)d_in[13];
  const float* cb  = (const float*)d_in[14];

  u16* bt = (u16*)d_ws;                         // [4096][2048] bf16 = 16 MiB
  u16* xh = bt + (size_t)4096 * 2048;           // [4096][2048] bf16 = 16 MiB
  float* hout = (float*)d_out;
  float* cout = hout + (size_t)BATCH * HID;

  prep_all<<<6144, 256, 0, stream>>>(x, hp, igx, fgx, ogx, cgx,
                                     igu, fgu, ogu, cgu, xh, bt);
  lstm_gemm<<<512, 256, 0, stream>>>(xh, bt, cp, ib, fb, ob, cb,
                                     hout, cout);
}

// Round 10
// 212.930 us; speedup vs baseline: 1.0033x; 1.0033x over previous
//
#include <hip/hip_runtime.h>
#include <hip/hip_bf16.h>

typedef unsigned short u16;
typedef unsigned int u32;
typedef short bf16x8 __attribute__((ext_vector_type(8)));
typedef float f32x4 __attribute__((ext_vector_type(4)));
typedef u16 u16x8 __attribute__((ext_vector_type(8)));

#define HID 1024
#define BATCH 4096
#define KTOT 2048       // concat K: [x | h_prev]
#define NT 64           // K tiles of 32
// LDS element-index region bases: [A buf0 | A buf1 | B buf0 | B buf1]
#define A0B 0
#define A1B 8192
#define B0B 16384
#define B1B 20480

__device__ __forceinline__ u16 f2bf(float f) {
  u32 v = __builtin_bit_cast(u32, f);
  u32 r = (v + 0x7fffu + ((v >> 16) & 1u)) >> 16;  // round-nearest-even
  return (u16)r;
}
__device__ __forceinline__ float sigmoid_fast(float x) {
  return 1.0f / (1.0f + __expf(-x));
}
__device__ __forceinline__ float tanh_fast(float x) {
  return 2.0f * sigmoid_fast(2.0f * x) - 1.0f;
}
__device__ __forceinline__ void gl_lds16(const void* g, void* l) {
  __builtin_amdgcn_global_load_lds(
      (const __attribute__((address_space(1))) u32*)g,
      (__attribute__((address_space(3))) u32*)l, 16, 0, 0);
}

// ---------------------------------------------------------------------------
// prep_all: fused prep. Blocks [0,4096) build xh (bf16 [B][2048]); blocks
// [4096,6144) build Bt[n'][k] (bf16, gate-interleaved n') via LDS transpose.
// ---------------------------------------------------------------------------
__global__ __launch_bounds__(256) void prep_all(
    const float* __restrict__ x, const float* __restrict__ hp,
    const float* __restrict__ igx, const float* __restrict__ fgx,
    const float* __restrict__ ogx, const float* __restrict__ cgx,
    const float* __restrict__ igu, const float* __restrict__ fgu,
    const float* __restrict__ ogu, const float* __restrict__ cgu,
    u16* __restrict__ xh, u16* __restrict__ bt) {
  __shared__ u16 lds[64 * 66];
  if (blockIdx.x < 4096) {
    int c = blockIdx.x * 256 + threadIdx.x;  // chunk id, 8 elems each
    int row = c >> 8;
    int col0 = (c & 255) << 3;
    const float* src = (col0 < 1024)
                           ? (x + (size_t)row * 1024 + col0)
                           : (hp + (size_t)row * 1024 + (col0 - 1024));
    f32x4 a = *(const f32x4*)(src);
    f32x4 b = *(const f32x4*)(src + 4);
    u16x8 v;
#pragma unroll
    for (int j = 0; j < 4; ++j) { v[j] = f2bf(a[j]); v[j + 4] = f2bf(b[j]); }
    *(u16x8*)(xh + (size_t)row * KTOT + col0) = v;
    return;
  }
  // ---- weight transpose: n' = (h/16)*64 + g*16 + (h%16), k = which*1024+ksrc
  const float* srcs[8] = {igx, fgx, ogx, cgx, igu, fgu, ogu, cgu};
  int bid = blockIdx.x - 4096;
  int m = bid >> 8;            // matrix 0..7
  int tile = bid & 255;        // 64x64 tile
  int th = tile & 15, tk = tile >> 4;
  int h0 = th << 6, k0 = tk << 6;
  int g = m & 3, which = m >> 2;
  const float* W = srcs[m] + (size_t)k0 * HID + h0;

  int t = threadIdx.x;
  int r1 = t >> 4;
  int c1 = (t & 15) << 2;
#pragma unroll
  for (int p = 0; p < 4; ++p) {
    int row = (p << 4) + r1;
    f32x4 v = *(const f32x4*)(W + (size_t)row * HID + c1);
    u32 p0 = (u32)f2bf(v[0]) | ((u32)f2bf(v[1]) << 16);
    u32 p1 = (u32)f2bf(v[2]) | ((u32)f2bf(v[3]) << 16);
    u32* d = (u32*)&lds[row * 66 + c1];
    d[0] = p0;
    d[1] = p1;
  }
  __syncthreads();
  int nl = t >> 2;
  int kc = t & 3;
  int row_np = ((h0 >> 4) << 6) + ((nl >> 4) << 6) + (g << 4) + (nl & 15);
  size_t dst = (size_t)row_np * KTOT + (size_t)which * 1024 + k0;
  u16x8 a2, b2;
#pragma unroll
  for (int j = 0; j < 8; ++j) {
    a2[j] = lds[(kc * 8 + j) * 66 + nl];
    b2[j] = lds[(kc * 8 + 32 + j) * 66 + nl];
  }
  *(u16x8*)(&bt[dst + kc * 8]) = a2;
  *(u16x8*)(&bt[dst + kc * 8 + 32]) = b2;
}

// ---------------------------------------------------------------------------
// lstm_gemm (R10): R9 structure — 256M x 128N tile, 256 threads (4 waves,
// 2Mx2N of 128x64), BK=32, 48 KiB LDS dbuf, grid 512 = 2 blocks/CU, one
// barrier per K-tile, stage-at-top, T1 XCD swizzle — with the BK=32 bank
// swizzle FIXED. R9 used key (row&3): with 16-dword rows (64B), bank quad =
// 16*(row&1) + 4*chunk, so lanes lrow and lrow+4 collided -> 6.29M conflicts
// (same as R8), confounding the 2-block overlap test. Correct key is
// ((row>>1)&3): each (quad,half) is hit by exactly 8 lanes x 4 dwords =
// 8 accesses/bank = the b128 minimum (conflict-free). Applied on the GLOBAL
// source (both-sides rule); read key ((wr+i*16+lrow)>>1)&3 == (lrow>>1)&3
// since all row bases are multiples of 16. Single variable vs R9.
// ---------------------------------------------------------------------------
__global__ __launch_bounds__(256, 2) void lstm_gemm(
    const u16* __restrict__ xh, const u16* __restrict__ bt,
    const float* __restrict__ cprev,
    const float* __restrict__ ib, const float* __restrict__ fb,
    const float* __restrict__ ob, const float* __restrict__ cb,
    float* __restrict__ hout, float* __restrict__ cout) {
  __shared__ __align__(16) u16 lds[24576];   // 48 KiB

  int sx = threadIdx.x;
  // T1: bid%8 -> XCD; XCD k owns brows [4*(k&3),+4), bcols [16*(k>>2),+16)
  int bid = blockIdx.x;
  int xcd = bid & 7, lid = bid >> 3;               // lid 0..63
  int brow = ((xcd & 3) << 2) | (lid & 3);         // 0..15
  int bcol = ((xcd >> 2) << 4) | (lid >> 2);       // 0..31

  int w = sx >> 6, l = sx & 63;
  int wr = (w >> 1) << 7;              // 0 | 128 (WARPS_M = 2)
  int wc = (w & 1) << 6;               // 0 | 64  (WARPS_N = 2)
  int lrow = l & 15, q = l >> 4;
  int grow = brow << 8;

  // staging source pointers; global addr carries the FIXED k-chunk swizzle
  int prow = sx >> 2;                                    // 0..63
  int koff = ((sx & 3) ^ ((prow >> 1) & 3)) << 3;        // key (row>>1)&3
  const u16* aS = xh + (size_t)(grow + prow) * KTOT + koff;
  const u16* bS = bt + (size_t)(bcol * 128 + prow) * KTOT + koff;
  int sx8 = sx * 8;

  // fragment read offsets: physical chunk = logical ^ ((row>>1)&3)
  int arow_l = (wr + lrow) << 5;            // *32 elems per row
  int brow_l = (wc + lrow) << 5;
  int pc = (q ^ ((lrow >> 1) & 3)) << 3;    // lane's k-chunk (q = l>>4)

  f32x4 acc[8][4] = {};
  bf16x8 af[8], bfr[4];

  // stage one K-tile (A 256 rows + B 128 rows) into bases AD_, BD_
#define STG(KK_, AD_, BD_)                                                    \
  gl_lds16(aS + (KK_), &lds[(AD_) + sx8]);                                    \
  gl_lds16(aS + (size_t)64 * KTOT + (KK_), &lds[(AD_) + 2048 + sx8]);         \
  gl_lds16(aS + (size_t)128 * KTOT + (KK_), &lds[(AD_) + 4096 + sx8]);        \
  gl_lds16(aS + (size_t)192 * KTOT + (KK_), &lds[(AD_) + 6144 + sx8]);        \
  gl_lds16(bS + (KK_), &lds[(BD_) + sx8]);                                    \
  gl_lds16(bS + (size_t)64 * KTOT + (KK_), &lds[(BD_) + 2048 + sx8]);

  // interior: 12 b128 reads + 32 MFMA, compiler-scheduled (partial lgkmcnt)
#define INTERIOR(AC_, BC_)                                                    \
  bfr[0] = *(const bf16x8*)&lds[(BC_) + brow_l + 0 * 512 + pc];               \
  bfr[1] = *(const bf16x8*)&lds[(BC_) + brow_l + 1 * 512 + pc];               \
  bfr[2] = *(const bf16x8*)&lds[(BC_) + brow_l + 2 * 512 + pc];               \
  bfr[3] = *(const bf16x8*)&lds[(BC_) + brow_l + 3 * 512 + pc];               \
  _Pragma("unroll") for (int i = 0; i < 8; ++i)                               \
      af[i] = *(const bf16x8*)&lds[(AC_) + arow_l + i * 512 + pc];            \
  _Pragma("unroll") for (int i = 0; i < 8; ++i) {                             \
    _Pragma("unroll") for (int j = 0; j < 4; ++j) {                           \
      acc[i][j] = __builtin_amdgcn_mfma_f32_16x16x32_bf16(                    \
          af[i], bfr[j], acc[i][j], 0, 0, 0);                                 \
    }                                                                         \
  }

#define TILE(AC_, BC_, KN_, AD_, BD_)                                         \
  {                                                                           \
    STG((KN_), (AD_), (BD_))                                                  \
    __builtin_amdgcn_sched_barrier(0);                                        \
    INTERIOR(AC_, BC_)                                                        \
  }

  // prologue: tile 0
  STG(0, A0B, B0B)
  __syncthreads();

  // tiles 0..61 in pairs; stage tile t+1 into the other buffer
  for (int tp = 0; tp < 31; ++tp) {
    int k1 = (2 * tp + 1) << 5;
    int k2 = (2 * tp + 2) << 5;
    TILE(A0B, B0B, k1, A1B, B1B)
    __syncthreads();
    TILE(A1B, B1B, k2, A0B, B0B)
    __syncthreads();
  }
  // tile 62: stage tile 63; tile 63: no stage
  TILE(A0B, B0B, 63 << 5, A1B, B1B)
  __syncthreads();
  INTERIOR(A1B, B1B)

#undef TILE
#undef INTERIOR
#undef STG

  // Epilogue: n-frag j = gate (i,f,o,c) for hidden cols of sub-block sb.
  int sb = (bcol << 1) + (w & 1);
  int hcol = (sb << 4) + lrow;
  float bi = ib[hcol];
  float bff = fb[hcol];
  float bo = ob[hcol];
  float bc = cb[hcol];

#pragma unroll
  for (int i = 0; i < 8; ++i) {
    int row0 = grow + wr + i * 16 + q * 4;
#pragma unroll
    for (int r = 0; r < 4; ++r) {
      size_t idx = (size_t)(row0 + r) * HID + hcol;
      float gi = sigmoid_fast(acc[i][0][r] + bi);
      float gf = sigmoid_fast(acc[i][1][r] + bff);
      float go = sigmoid_fast(acc[i][2][r] + bo);
      float gc = tanh_fast(acc[i][3][r] + bc);
      float cp = cprev[idx];
      float cv = gf * cp + gi * gc;
      hout[idx] = go * tanh_fast(cv);
      cout[idx] = cv;
    }
  }
}

extern "C" void kernel_launch(void* const* d_in, const int* in_sizes, int n_in,
                              void* d_out, int out_size, void* d_ws, size_t ws_size,
                              hipStream_t stream) {
  const float* x   = (const float*)d_in[0];
  const float* hp  = (const float*)d_in[1];
  const float* cp  = (const float*)d_in[2];
  const float* igx = (const float*)d_in[3];
  const float* igu = (const float*)d_in[4];
  const float* ib  = (const float*)d_in[5];
  const float* fgx = (const float*)d_in[6];
  const float* fgu = (const float*)d_in[7];
  const float* fb  = (const float*)d_in[8];
  const float* ogx = (const float*)d_in[9];
  const float* ogu = (const float*)d_in[10];
  const float* ob  = (const float*)d_in[11];
  const float* cgx = (const float*)d_in[12];
  const float* cgu = (const float*)d_in[13];
  const float* cb  = (const float*)d_in[14];

  u16* bt = (u16*)d_ws;                         // [4096][2048] bf16 = 16 MiB
  u16* xh = bt + (size_t)4096 * 2048;           // [4096][2048] bf16 = 16 MiB
  float* hout = (float*)d_out;
  float* cout = hout + (size_t)BATCH * HID;

  prep_all<<<6144, 256, 0, stream>>>(x, hp, igx, fgx, ogx, cgx,
                                     igu, fgu, ogu, cgu, xh, bt);
  lstm_gemm<<<512, 256, 0, stream>>>(xh, bt, cp, ib, fb, ob, cb,
                                     hout, cout);
}